// Round 3
// baseline (442.488 us; speedup 1.0000x reference)
//
#include <hip/hip_runtime.h>
#include <hip/hip_bf16.h>

#define LSEQ 2048
#define BB 2
#define DD 128
#define HH 8
#define HD 32

typedef __bf16 bf8_t __attribute__((ext_vector_type(8)));
typedef float f4_t __attribute__((ext_vector_type(4)));

// ---------------- kernel 0a: xp = bf16(x + pe) ----------------
__global__ __launch_bounds__(256) void k_xpb(const float* __restrict__ x,
                                             const float* __restrict__ pe,
                                             __bf16* __restrict__ xpb) {
    int idx = blockIdx.x * 256 + threadIdx.x;     // 0..524287 (4096*128)
    int d = idx & 127;
    int l = (idx >> 7) & (LSEQ - 1);
    float v = x[idx] + pe[l * DD + d];
    xpb[idx] = (__bf16)v;
}

// ---------------- kernel 0b: transpose Wq/Wk -> [c][d] bf16 ----------------
__global__ __launch_bounds__(256) void k_wtrans(const float* __restrict__ Wq,
                                                const float* __restrict__ Wk,
                                                __bf16* __restrict__ WqT,
                                                __bf16* __restrict__ WkT) {
    __shared__ float tile[32][33];
    const float* W = blockIdx.z ? Wk : Wq;
    __bf16* WT = blockIdx.z ? WkT : WqT;
    int d0 = blockIdx.x * 32, c0 = blockIdx.y * 32;
    int tr = threadIdx.x >> 5, tc = threadIdx.x & 31;
    for (int i = 0; i < 4; i++)
        tile[tr + i * 8][tc] = W[(d0 + tr + i * 8) * 256 + c0 + tc];
    __syncthreads();
    for (int i = 0; i < 4; i++)
        WT[(c0 + tr + i * 8) * 128 + d0 + tc] = (__bf16)tile[tc][tr + i * 8];
}

// ---------------- kernel 0c: w[hb][k] = sigmoid(x[b,L-1-k] . Wv[:,h]) ------
__global__ __launch_bounds__(256) void k_wv(const float* __restrict__ x,
                                            const float* __restrict__ Wv,
                                            float* __restrict__ w) {
    __shared__ float xs[32 * 132];
    __shared__ float wv[128 * 8];
    int r0 = blockIdx.x * 32;                       // 32 rows per block
    for (int i = 0; i < 16; i++) {
        int idx = threadIdx.x + i * 256;            // 0..4095
        xs[(idx >> 7) * 132 + (idx & 127)] = x[r0 * 128 + idx];
    }
    for (int i = 0; i < 4; i++) {
        int idx = threadIdx.x + i * 256;            // 0..1023
        wv[idx] = Wv[idx];
    }
    __syncthreads();
    int rl = threadIdx.x >> 3, h = threadIdx.x & 7;
    float acc = 0.f;
    #pragma unroll 8
    for (int d = 0; d < 128; d++) acc += xs[rl * 132 + d] * wv[d * 8 + h];
    float sg = 1.f / (1.f + __expf(-acc));
    int r = r0 + rl;
    int b = r >> 11, l = r & (LSEQ - 1);
    w[(h * BB + b) * LSEQ + (LSEQ - 1 - l)] = sg;
}

// ---------------- kernel 1: Q/K = xp @ W (+bias), MFMA, store bf16 ---------
__global__ __launch_bounds__(256) void k_qk(const __bf16* __restrict__ xpb,
                                            const __bf16* __restrict__ WqT,
                                            const __bf16* __restrict__ WkT,
                                            const float* __restrict__ bq,
                                            const float* __restrict__ bk,
                                            __bf16* __restrict__ Qb,
                                            __bf16* __restrict__ Kb) {
    // grid (256, 8); wave computes a 16x16 output tile, K-dim 128
    int wid = threadIdx.x >> 6, lane = threadIdx.x & 63;
    int row0 = blockIdx.x * 16;
    int col0 = blockIdx.y * 64 + wid * 16;          // 0..511
    bool isK = col0 >= 256;
    int c0 = isK ? col0 - 256 : col0;
    const __bf16* WT = isK ? WkT : WqT;
    const float* bias = isK ? bk : bq;
    __bf16* Out = isK ? Kb : Qb;

    int lm = lane & 15, lq = lane >> 4;
    f4_t acc = {0.f, 0.f, 0.f, 0.f};
    const __bf16* aptr = xpb + (row0 + lm) * 128 + lq * 8;
    const __bf16* bptr = WT + (c0 + lm) * 128 + lq * 8;
    #pragma unroll
    for (int s = 0; s < 4; s++) {
        bf8_t a = *(const bf8_t*)(aptr + s * 32);
        bf8_t bfr = *(const bf8_t*)(bptr + s * 32);
        acc = __builtin_amdgcn_mfma_f32_16x16x32_bf16(a, bfr, acc, 0, 0, 0);
    }
    int c = c0 + lm;
    float bv = bias[c];
    int h = c >> 5, hd = c & 31;
    #pragma unroll
    for (int r = 0; r < 4; r++) {
        int row = row0 + lq * 4 + r;                // = b*2048 + l
        int b_ = row >> 11, l = row & (LSEQ - 1);
        Out[((h * BB + b_) * LSEQ + l) * HD + hd] = (__bf16)(acc[r] + bv);
    }
}

// ---------------- zero S (32K floats) + den (32K floats) ----------------
__global__ __launch_bounds__(256) void k_zero2(float* __restrict__ S,
                                               float* __restrict__ den) {
    int idx = blockIdx.x * 256 + threadIdx.x;       // 0..65535
    if (idx < 32768) S[idx] = 0.f;
    else den[idx - 32768] = 0.f;
}

// ---------------- kernel 2a: softmax denominators (no LDS, no barriers) ----
__global__ __launch_bounds__(256) void k_den(const __bf16* __restrict__ Qb,
                                             const __bf16* __restrict__ Kb,
                                             float* __restrict__ den) {
    int hb = blockIdx.z;
    int q0 = blockIdx.y * 64;
    int kbase = blockIdx.x * 1024;                  // k-half
    int wid = threadIdx.x >> 6, lane = threadIdx.x & 63;
    int lm = lane & 15, lq = lane >> 4;
    int qw0 = q0 + wid * 16;

    bf8_t aq = *(const bf8_t*)(Qb + (hb * LSEQ + qw0 + lm) * HD + lq * 8);
    const __bf16* Khb = Kb + hb * LSEQ * HD;
    const float scale = 0.17677669529663687f;       // 1/sqrt(32)

    float dsum[4] = {0.f, 0.f, 0.f, 0.f};
    #pragma unroll 4
    for (int s = 0; s < 64; s++) {
        int k0 = kbase + s * 16;
        bf8_t bk_ = *(const bf8_t*)(Khb + (k0 + lm) * HD + lq * 8);
        f4_t z = {0.f, 0.f, 0.f, 0.f};
        f4_t sc = __builtin_amdgcn_mfma_f32_16x16x32_bf16(aq, bk_, z, 0, 0, 0);
        #pragma unroll
        for (int r = 0; r < 4; r++) dsum[r] += __expf(sc[r] * scale);
    }
    #pragma unroll
    for (int r = 0; r < 4; r++) {
        float v = dsum[r];
        v += __shfl_xor(v, 1);
        v += __shfl_xor(v, 2);
        v += __shfl_xor(v, 4);
        v += __shfl_xor(v, 8);
        dsum[r] = v;
    }
    if (lm == 0) {
        #pragma unroll
        for (int r = 0; r < 4; r++)
            atomicAdd(&den[hb * LSEQ + qw0 + lq * 4 + r], dsum[r]);
    }
}

// ---------------- kernel 2b: triangle scatter (2 barriers total) -----------
__global__ __launch_bounds__(256) void k_scat(const __bf16* __restrict__ Qb,
                                              const __bf16* __restrict__ Kb,
                                              const float* __restrict__ w,
                                              const float* __restrict__ den,
                                              float* __restrict__ S) {
    int hb = blockIdx.z;
    int q0 = blockIdx.y * 64;
    int kc0 = blockIdx.x * 256;
    if (kc0 + 256 <= q0) return;                    // entirely below diagonal

    __shared__ float Sloc[320];
    __shared__ float wt[256];
    int tid = threadIdx.x;
    Sloc[tid >= 64 ? tid : tid + 256] = 0.f;        // covers 64..319 via tid, 256..319 via tid<64
    if (tid < 64) Sloc[tid] = 0.f;
    wt[tid] = w[hb * LSEQ + kc0 + tid];

    int wid = tid >> 6, lane = tid & 63;
    int lm = lane & 15, lq = lane >> 4;
    int qw0 = q0 + wid * 16;
    bf8_t aq = *(const bf8_t*)(Qb + (hb * LSEQ + qw0 + lm) * HD + lq * 8);
    float rdv[4];
    #pragma unroll
    for (int r = 0; r < 4; r++)
        rdv[r] = 1.f / den[hb * LSEQ + qw0 + lq * 4 + r];
    __syncthreads();

    const __bf16* Khb = Kb + hb * LSEQ * HD;
    const float scale = 0.17677669529663687f;
    int mbase = kc0 - q0 - 63;
    int qrow = qw0 + lq * 4;

    #pragma unroll 2
    for (int sub = 0; sub < 16; sub++) {
        int k0s = kc0 + sub * 16;
        if (k0s + 15 < qw0) continue;               // subtile fully below diagonal
        bf8_t bk_ = *(const bf8_t*)(Khb + (k0s + lm) * HD + lq * 8);
        f4_t z = {0.f, 0.f, 0.f, 0.f};
        f4_t sc = __builtin_amdgcn_mfma_f32_16x16x32_bf16(aq, bk_, z, 0, 0, 0);
        float wv = wt[sub * 16 + lm];
        int kcol = k0s + lm;
        #pragma unroll
        for (int r = 0; r < 4; r++) {
            int m = kcol - (qrow + r);
            if (m >= 0) {
                float val = __expf(sc[r] * scale) * wv * rdv[r];
                __hip_atomic_fetch_add(&Sloc[m - mbase], val, __ATOMIC_RELAXED,
                                       __HIP_MEMORY_SCOPE_WORKGROUP);
            }
        }
    }
    __syncthreads();
    for (int i = tid; i < 320; i += 256) {
        int m = mbase + i;
        if (m >= 0 && m < LSEQ)
            atomicAdd(&S[hb * LSEQ + m], Sloc[i]);
    }
}

// ---------------- kernel 3: pooling epilogue ----------------
__global__ __launch_bounds__(256) void k_out(const float* __restrict__ S,
                                             float* __restrict__ out) {
    int idx = blockIdx.x * 256 + threadIdx.x;       // (b*2048 + m)*8 + h
    int h = idx & 7;
    int m = (idx >> 3) & (LSEQ - 1);
    int b = idx >> 14;
    const float* Sr = S + (h * BB + b) * LSEQ;
    float s = Sr[m];
    float cnt = 3.f;
    if (m > 0) s += Sr[m - 1]; else cnt = 2.f;
    if (m < LSEQ - 1) s += Sr[m + 1]; else cnt = 2.f;
    out[idx] = s / cnt;
}

extern "C" void kernel_launch(void* const* d_in, const int* in_sizes, int n_in,
                              void* d_out, int out_size, void* d_ws, size_t ws_size,
                              hipStream_t stream) {
    const float* x  = (const float*)d_in[0];
    const float* pe = (const float*)d_in[1];
    const float* Wq = (const float*)d_in[2];
    const float* bq = (const float*)d_in[3];
    const float* Wk = (const float*)d_in[4];
    const float* bk = (const float*)d_in[5];
    const float* Wv = (const float*)d_in[6];
    float* out = (float*)d_out;

    char* ws = (char*)d_ws;
    float*  S    = (float*)(ws);                            // 128 KB
    float*  w    = (float*)(ws + 131072);                   // 128 KB
    __bf16* Qb   = (__bf16*)(ws + 262144);                  // 2 MB
    __bf16* Kb   = (__bf16*)(ws + 262144 + 2097152);        // 2 MB
    __bf16* xpb  = (__bf16*)(ws + 262144 + 4194304);        // 1 MB
    __bf16* WqT  = (__bf16*)(ws + 262144 + 4194304 + 1048576);   // 64 KB
    __bf16* WkT  = (__bf16*)(ws + 262144 + 4194304 + 1048576 + 65536);
    float*  den  = (float*)xpb;  // xpb is dead after k_qk; reuse for den (128 KB)

    k_xpb<<<2048, 256, 0, stream>>>(x, pe, xpb);
    k_wtrans<<<dim3(4, 8, 2), 256, 0, stream>>>(Wq, Wk, WqT, WkT);
    k_wv<<<128, 256, 0, stream>>>(x, Wv, w);
    k_qk<<<dim3(256, 8), 256, 0, stream>>>(xpb, WqT, WkT, bq, bk, Qb, Kb);
    k_zero2<<<256, 256, 0, stream>>>(S, den);      // after k_qk: den aliases xpb
    k_den<<<dim3(2, 32, 16), 256, 0, stream>>>(Qb, Kb, den);
    k_scat<<<dim3(8, 32, 16), 256, 0, stream>>>(Qb, Kb, w, den, S);
    k_out<<<128, 256, 0, stream>>>(S, out);
}

// Round 4
// 137.785 us; speedup vs baseline: 3.2114x; 3.2114x over previous
//
#include <hip/hip_runtime.h>
#include <hip/hip_bf16.h>

#define LSEQ 2048
#define BB 2
#define DD 128
#define HH 8
#define HD 32

#define FPSCALE 524288.0f          // 2^19 fixed-point scale
#define RFPSCALE (1.0f / 524288.0f)

typedef __bf16 bf8_t __attribute__((ext_vector_type(8)));
typedef float f4_t __attribute__((ext_vector_type(4)));

// ---------------- kernel 0a: xp = bf16(x + pe) ----------------
__global__ __launch_bounds__(256) void k_xpb(const float* __restrict__ x,
                                             const float* __restrict__ pe,
                                             __bf16* __restrict__ xpb) {
    int idx = blockIdx.x * 256 + threadIdx.x;     // 0..524287 (4096*128)
    int d = idx & 127;
    int l = (idx >> 7) & (LSEQ - 1);
    float v = x[idx] + pe[l * DD + d];
    xpb[idx] = (__bf16)v;
}

// ---------------- kernel 0b: transpose Wq/Wk -> [c][d] bf16 ----------------
__global__ __launch_bounds__(256) void k_wtrans(const float* __restrict__ Wq,
                                                const float* __restrict__ Wk,
                                                __bf16* __restrict__ WqT,
                                                __bf16* __restrict__ WkT) {
    __shared__ float tile[32][33];
    const float* W = blockIdx.z ? Wk : Wq;
    __bf16* WT = blockIdx.z ? WkT : WqT;
    int d0 = blockIdx.x * 32, c0 = blockIdx.y * 32;
    int tr = threadIdx.x >> 5, tc = threadIdx.x & 31;
    for (int i = 0; i < 4; i++)
        tile[tr + i * 8][tc] = W[(d0 + tr + i * 8) * 256 + c0 + tc];
    __syncthreads();
    for (int i = 0; i < 4; i++)
        WT[(c0 + tr + i * 8) * 128 + d0 + tc] = (__bf16)tile[tc][tr + i * 8];
}

// ---------------- kernel 0c: w[hb][k] = sigmoid(x[b,L-1-k] . Wv[:,h]) ------
__global__ __launch_bounds__(256) void k_wv(const float* __restrict__ x,
                                            const float* __restrict__ Wv,
                                            float* __restrict__ w) {
    __shared__ float xs[32 * 132];
    __shared__ float wv[128 * 8];
    int r0 = blockIdx.x * 32;                       // 32 rows per block
    for (int i = 0; i < 16; i++) {
        int idx = threadIdx.x + i * 256;            // 0..4095
        xs[(idx >> 7) * 132 + (idx & 127)] = x[r0 * 128 + idx];
    }
    for (int i = 0; i < 4; i++) {
        int idx = threadIdx.x + i * 256;            // 0..1023
        wv[idx] = Wv[idx];
    }
    __syncthreads();
    int rl = threadIdx.x >> 3, h = threadIdx.x & 7;
    float acc = 0.f;
    #pragma unroll 8
    for (int d = 0; d < 128; d++) acc += xs[rl * 132 + d] * wv[d * 8 + h];
    float sg = 1.f / (1.f + __expf(-acc));
    int r = r0 + rl;
    int b = r >> 11, l = r & (LSEQ - 1);
    w[(h * BB + b) * LSEQ + (LSEQ - 1 - l)] = sg;
}

// ---------------- kernel 1: Q/K = xp @ W (+bias), MFMA, store bf16 ---------
__global__ __launch_bounds__(256) void k_qk(const __bf16* __restrict__ xpb,
                                            const __bf16* __restrict__ WqT,
                                            const __bf16* __restrict__ WkT,
                                            const float* __restrict__ bq,
                                            const float* __restrict__ bk,
                                            __bf16* __restrict__ Qb,
                                            __bf16* __restrict__ Kb) {
    // grid (256, 8); wave computes a 16x16 output tile, K-dim 128
    int wid = threadIdx.x >> 6, lane = threadIdx.x & 63;
    int row0 = blockIdx.x * 16;
    int col0 = blockIdx.y * 64 + wid * 16;          // 0..511
    bool isK = col0 >= 256;
    int c0 = isK ? col0 - 256 : col0;
    const __bf16* WT = isK ? WkT : WqT;
    const float* bias = isK ? bk : bq;
    __bf16* Out = isK ? Kb : Qb;

    int lm = lane & 15, lq = lane >> 4;
    f4_t acc = {0.f, 0.f, 0.f, 0.f};
    const __bf16* aptr = xpb + (row0 + lm) * 128 + lq * 8;
    const __bf16* bptr = WT + (c0 + lm) * 128 + lq * 8;
    #pragma unroll
    for (int s = 0; s < 4; s++) {
        bf8_t a = *(const bf8_t*)(aptr + s * 32);
        bf8_t bfr = *(const bf8_t*)(bptr + s * 32);
        acc = __builtin_amdgcn_mfma_f32_16x16x32_bf16(a, bfr, acc, 0, 0, 0);
    }
    int c = c0 + lm;
    float bv = bias[c];
    int h = c >> 5, hd = c & 31;
    #pragma unroll
    for (int r = 0; r < 4; r++) {
        int row = row0 + lq * 4 + r;                // = b*2048 + l
        int b_ = row >> 11, l = row & (LSEQ - 1);
        Out[((h * BB + b_) * LSEQ + l) * HD + hd] = (__bf16)(acc[r] + bv);
    }
}

// ---------------- zero S_int (32K ints) ----------------
__global__ __launch_bounds__(256) void k_zeroS(int* __restrict__ S) {
    S[blockIdx.x * 256 + threadIdx.x] = 0;
}

// ---------------- kernel 2a: reciprocal softmax denominators ---------------
// One block owns 64 q-rows over the FULL k range -> plain store, no atomics.
__global__ __launch_bounds__(256) void k_den(const __bf16* __restrict__ Qb,
                                             const __bf16* __restrict__ Kb,
                                             float* __restrict__ rden) {
    int hb = blockIdx.y;
    int q0 = blockIdx.x * 64;
    int wid = threadIdx.x >> 6, lane = threadIdx.x & 63;
    int lm = lane & 15, lq = lane >> 4;
    int qw0 = q0 + wid * 16;

    bf8_t aq = *(const bf8_t*)(Qb + (hb * LSEQ + qw0 + lm) * HD + lq * 8);
    const __bf16* Khb = Kb + hb * LSEQ * HD;
    const float scale = 0.17677669529663687f;       // 1/sqrt(32)

    float dsum[4] = {0.f, 0.f, 0.f, 0.f};
    #pragma unroll 8
    for (int s = 0; s < 128; s++) {
        bf8_t bk_ = *(const bf8_t*)(Khb + (s * 16 + lm) * HD + lq * 8);
        f4_t z = {0.f, 0.f, 0.f, 0.f};
        f4_t sc = __builtin_amdgcn_mfma_f32_16x16x32_bf16(aq, bk_, z, 0, 0, 0);
        #pragma unroll
        for (int r = 0; r < 4; r++) dsum[r] += __expf(sc[r] * scale);
    }
    #pragma unroll
    for (int r = 0; r < 4; r++) {
        float v = dsum[r];
        v += __shfl_xor(v, 1);
        v += __shfl_xor(v, 2);
        v += __shfl_xor(v, 4);
        v += __shfl_xor(v, 8);
        dsum[r] = v;
    }
    if (lm == 0) {
        #pragma unroll
        for (int r = 0; r < 4; r++)
            rden[hb * LSEQ + qw0 + lq * 4 + r] = 1.f / dsum[r];
    }
}

// ---------------- kernel 2b: triangle scatter, int fixed-point -------------
__global__ __launch_bounds__(256) void k_scat(const __bf16* __restrict__ Qb,
                                              const __bf16* __restrict__ Kb,
                                              const float* __restrict__ w,
                                              const float* __restrict__ rden,
                                              int* __restrict__ S) {
    int hb = blockIdx.z;
    int q0 = blockIdx.y * 64;
    int kc0 = blockIdx.x * 256;
    if (kc0 + 256 <= q0) return;                    // entirely below diagonal

    __shared__ int Sloc[320];
    __shared__ float wt[256];
    int tid = threadIdx.x;
    for (int i = tid; i < 320; i += 256) Sloc[i] = 0;
    wt[tid] = w[hb * LSEQ + kc0 + tid] * FPSCALE;   // fold fixed-point scale in

    int wid = tid >> 6, lane = tid & 63;
    int lm = lane & 15, lq = lane >> 4;
    int qw0 = q0 + wid * 16;
    bf8_t aq = *(const bf8_t*)(Qb + (hb * LSEQ + qw0 + lm) * HD + lq * 8);
    float rdv[4];
    #pragma unroll
    for (int r = 0; r < 4; r++)
        rdv[r] = rden[hb * LSEQ + qw0 + lq * 4 + r];
    __syncthreads();

    const __bf16* Khb = Kb + hb * LSEQ * HD;
    const float scale = 0.17677669529663687f;
    int mbase = kc0 - q0 - 63;
    int qrow = qw0 + lq * 4;

    #pragma unroll 2
    for (int sub = 0; sub < 16; sub++) {
        int k0s = kc0 + sub * 16;
        if (k0s + 15 < qw0) continue;               // subtile fully below diagonal
        bf8_t bk_ = *(const bf8_t*)(Khb + (k0s + lm) * HD + lq * 8);
        f4_t z = {0.f, 0.f, 0.f, 0.f};
        f4_t sc = __builtin_amdgcn_mfma_f32_16x16x32_bf16(aq, bk_, z, 0, 0, 0);
        float wvs = wt[sub * 16 + lm];              // w * 2^19
        int kcol = k0s + lm;
        #pragma unroll
        for (int r = 0; r < 4; r++) {
            int m = kcol - (qrow + r);
            if (m >= 0) {
                int iv = __float2int_rn(__expf(sc[r] * scale) * rdv[r] * wvs);
                atomicAdd(&Sloc[m - mbase], iv);    // native ds_add_u32
            }
        }
    }
    __syncthreads();
    for (int i = tid; i < 320; i += 256) {
        int m = mbase + i;
        int v = Sloc[i];
        if (m >= 0 && m < LSEQ && v != 0)
            atomicAdd(&S[hb * LSEQ + m], v);        // native int global atomic
    }
}

// ---------------- kernel 3: pooling epilogue (int -> float) ----------------
__global__ __launch_bounds__(256) void k_out(const int* __restrict__ S,
                                             float* __restrict__ out) {
    int idx = blockIdx.x * 256 + threadIdx.x;       // (b*2048 + m)*8 + h
    int h = idx & 7;
    int m = (idx >> 3) & (LSEQ - 1);
    int b = idx >> 14;
    const int* Sr = S + (h * BB + b) * LSEQ;
    float s = (float)Sr[m];
    float cnt = 3.f;
    if (m > 0) s += (float)Sr[m - 1]; else cnt = 2.f;
    if (m < LSEQ - 1) s += (float)Sr[m + 1]; else cnt = 2.f;
    out[idx] = s * RFPSCALE / cnt;
}

extern "C" void kernel_launch(void* const* d_in, const int* in_sizes, int n_in,
                              void* d_out, int out_size, void* d_ws, size_t ws_size,
                              hipStream_t stream) {
    const float* x  = (const float*)d_in[0];
    const float* pe = (const float*)d_in[1];
    const float* Wq = (const float*)d_in[2];
    const float* bq = (const float*)d_in[3];
    const float* Wk = (const float*)d_in[4];
    const float* bk = (const float*)d_in[5];
    const float* Wv = (const float*)d_in[6];
    float* out = (float*)d_out;

    char* ws = (char*)d_ws;
    int*    Si   = (int*)(ws);                              // 128 KB
    float*  w    = (float*)(ws + 131072);                   // 128 KB
    __bf16* Qb   = (__bf16*)(ws + 262144);                  // 2 MB
    __bf16* Kb   = (__bf16*)(ws + 262144 + 2097152);        // 2 MB
    __bf16* xpb  = (__bf16*)(ws + 262144 + 4194304);        // 1 MB
    __bf16* WqT  = (__bf16*)(ws + 262144 + 4194304 + 1048576);   // 64 KB
    __bf16* WkT  = (__bf16*)(ws + 262144 + 4194304 + 1048576 + 65536);
    float*  rden = (float*)xpb;  // xpb dead after k_qk; reuse (128 KB)

    k_xpb<<<2048, 256, 0, stream>>>(x, pe, xpb);
    k_wtrans<<<dim3(4, 8, 2), 256, 0, stream>>>(Wq, Wk, WqT, WkT);
    k_wv<<<128, 256, 0, stream>>>(x, Wv, w);
    k_qk<<<dim3(256, 8), 256, 0, stream>>>(xpb, WqT, WkT, bq, bk, Qb, Kb);
    k_zeroS<<<128, 256, 0, stream>>>(Si);
    k_den<<<dim3(32, 16), 256, 0, stream>>>(Qb, Kb, rden);
    k_scat<<<dim3(8, 32, 16), 256, 0, stream>>>(Qb, Kb, w, rden, Si);
    k_out<<<128, 256, 0, stream>>>(Si, out);
}

// Round 6
// 133.338 us; speedup vs baseline: 3.3185x; 1.0334x over previous
//
#include <hip/hip_runtime.h>
#include <hip/hip_bf16.h>

#define LSEQ 2048
#define BB 2
#define DD 128
#define HH 8
#define HD 32

#define FPSCALE 524288.0f            // 2^19 fixed-point scale for S
#define RFPSCALE (1.0f / 524288.0f)
#define DENSCALE 65536.0f            // 2^16 fixed-point scale for den
#define QSCALE 0.25503486f           // (1/sqrt(32)) * log2(e)  -> use exp2

typedef __bf16 bf8_t __attribute__((ext_vector_type(8)));
typedef float f4_t __attribute__((ext_vector_type(4)));

// ---------------- kernel 0: fused prep ----------------
// blocks 0..63    : transpose Wq/Wk -> [c][d] bf16
// blocks 64..191  : w[hb][k] = sigmoid(x[b,L-1-k] . Wv[:,h])
// blocks 192..319 : zero Si
// blocks 320..447 : zero denI
__global__ __launch_bounds__(256) void k_prep(const float* __restrict__ x,
                                              const float* __restrict__ Wq,
                                              const float* __restrict__ Wk,
                                              const float* __restrict__ Wv,
                                              __bf16* __restrict__ WqT,
                                              __bf16* __restrict__ WkT,
                                              float* __restrict__ w,
                                              int* __restrict__ Si,
                                              int* __restrict__ denI) {
    __shared__ float tile[32][33];
    __shared__ float xs[32 * 132];
    __shared__ float wv[128 * 8];
    int gb = blockIdx.x;
    int tid = threadIdx.x;
    if (gb < 64) {
        int z = gb >> 5, t = gb & 31;
        const float* W = z ? Wk : Wq;
        __bf16* WT = z ? WkT : WqT;
        int d0 = (t & 3) * 32, c0 = (t >> 2) * 32;
        int tr = tid >> 5, tc = tid & 31;
        for (int i = 0; i < 4; i++)
            tile[tr + i * 8][tc] = W[(d0 + tr + i * 8) * 256 + c0 + tc];
        __syncthreads();
        for (int i = 0; i < 4; i++)
            WT[(c0 + tr + i * 8) * 128 + d0 + tc] = (__bf16)tile[tc][tr + i * 8];
    } else if (gb < 192) {
        int r0 = (gb - 64) * 32;
        for (int i = 0; i < 16; i++) {
            int idx = tid + i * 256;
            xs[(idx >> 7) * 132 + (idx & 127)] = x[r0 * 128 + idx];
        }
        for (int i = 0; i < 4; i++) {
            int idx = tid + i * 256;
            wv[idx] = Wv[idx];
        }
        __syncthreads();
        int rl = tid >> 3, h = tid & 7;
        float acc = 0.f;
        #pragma unroll 8
        for (int d = 0; d < 128; d++) acc += xs[rl * 132 + d] * wv[d * 8 + h];
        float sg = 1.f / (1.f + __expf(-acc));
        int r = r0 + rl;
        int b = r >> 11, l = r & (LSEQ - 1);
        w[(h * BB + b) * LSEQ + (LSEQ - 1 - l)] = sg;
    } else if (gb < 320) {
        Si[(gb - 192) * 256 + tid] = 0;
    } else {
        denI[(gb - 320) * 256 + tid] = 0;
    }
}

// ---------------- kernel 1: Q/K = (x+pe) @ W (+bias), MFMA ----------------
// Q is pre-scaled by QSCALE so scores feed exp2 directly.
__global__ __launch_bounds__(256) void k_qk(const float* __restrict__ x,
                                            const float* __restrict__ pe,
                                            const __bf16* __restrict__ WqT,
                                            const __bf16* __restrict__ WkT,
                                            const float* __restrict__ bq,
                                            const float* __restrict__ bk,
                                            __bf16* __restrict__ Qb,
                                            __bf16* __restrict__ Kb) {
    __shared__ __bf16 xs[16][136];                  // +8 pad: 2-way banks, 16B-aligned rows
    int tid = threadIdx.x;
    int row0 = blockIdx.x * 16;
    // stage x+pe -> bf16 LDS (16 rows x 128 cols)
    #pragma unroll
    for (int i = 0; i < 8; i++) {
        int idx = tid + i * 256;                    // 0..2047
        int row = idx >> 7, col = idx & 127;
        xs[row][col] = (__bf16)(x[row0 * 128 + idx] +
                                pe[((row0 + row) & (LSEQ - 1)) * 128 + col]);
    }
    __syncthreads();

    int wid = tid >> 6, lane = tid & 63;
    int col0 = blockIdx.y * 64 + wid * 16;          // 0..511
    bool isK = col0 >= 256;
    int c0 = isK ? col0 - 256 : col0;
    const __bf16* WT = isK ? WkT : WqT;
    const float* bias = isK ? bk : bq;
    __bf16* Out = isK ? Kb : Qb;

    int lm = lane & 15, lq = lane >> 4;
    f4_t acc = {0.f, 0.f, 0.f, 0.f};
    const __bf16* bptr = WT + (c0 + lm) * 128 + lq * 8;
    #pragma unroll
    for (int s = 0; s < 4; s++) {
        bf8_t a = *(const bf8_t*)(&xs[lm][lq * 8 + s * 32]);
        bf8_t bfr = *(const bf8_t*)(bptr + s * 32);
        acc = __builtin_amdgcn_mfma_f32_16x16x32_bf16(a, bfr, acc, 0, 0, 0);
    }
    int c = c0 + lm;
    float bv = bias[c];
    float qs = isK ? 1.f : QSCALE;
    int h = c >> 5, hd = c & 31;
    #pragma unroll
    for (int r = 0; r < 4; r++) {
        int row = row0 + lq * 4 + r;                // = b*2048 + l
        int b_ = row >> 11, l = row & (LSEQ - 1);
        Out[((h * BB + b_) * LSEQ + l) * HD + hd] = (__bf16)((acc[r] + bv) * qs);
    }
}

// ---------------- kernel 2a: fixed-point softmax denominators --------------
__global__ __launch_bounds__(256) void k_den(const __bf16* __restrict__ Qb,
                                             const __bf16* __restrict__ Kb,
                                             int* __restrict__ denI) {
    int hb = blockIdx.z;
    int q0 = blockIdx.y * 64;
    int kbase = blockIdx.x * 512;                   // k-quarter
    int wid = threadIdx.x >> 6, lane = threadIdx.x & 63;
    int lm = lane & 15, lq = lane >> 4;
    int qw0 = q0 + wid * 16;

    bf8_t aq = *(const bf8_t*)(Qb + (hb * LSEQ + qw0 + lm) * HD + lq * 8);
    const __bf16* Khb = Kb + hb * LSEQ * HD;

    float dsum[4] = {0.f, 0.f, 0.f, 0.f};
    #pragma unroll 4
    for (int s = 0; s < 32; s++) {
        bf8_t bk_ = *(const bf8_t*)(Khb + (kbase + s * 16 + lm) * HD + lq * 8);
        f4_t z = {0.f, 0.f, 0.f, 0.f};
        f4_t sc = __builtin_amdgcn_mfma_f32_16x16x32_bf16(aq, bk_, z, 0, 0, 0);
        #pragma unroll
        for (int r = 0; r < 4; r++) dsum[r] += exp2f(sc[r]);
    }
    #pragma unroll
    for (int r = 0; r < 4; r++) {
        float v = dsum[r];
        v += __shfl_xor(v, 1);
        v += __shfl_xor(v, 2);
        v += __shfl_xor(v, 4);
        v += __shfl_xor(v, 8);
        dsum[r] = v;
    }
    if (lm == 0) {
        #pragma unroll
        for (int r = 0; r < 4; r++)
            atomicAdd(&denI[hb * LSEQ + qw0 + lq * 4 + r],
                      __float2int_rn(dsum[r] * DENSCALE));
    }
}

// ---------------- kernel 2b: triangle scatter, per-wave LDS slices ---------
__global__ __launch_bounds__(256) void k_scat(const __bf16* __restrict__ Qb,
                                              const __bf16* __restrict__ Kb,
                                              const float* __restrict__ w,
                                              const int* __restrict__ denI,
                                              int* __restrict__ S) {
    int hb = blockIdx.z;
    int q0 = blockIdx.y * 64;
    int kc0 = blockIdx.x * 256;
    if (kc0 + 256 <= q0) return;                    // entirely below diagonal

    __shared__ int Sloc[4 * 320];
    __shared__ float wt[256];
    int tid = threadIdx.x;
    for (int i = tid; i < 1280; i += 256) Sloc[i] = 0;
    wt[tid] = w[hb * LSEQ + kc0 + tid] * FPSCALE;   // fold fixed-point scale in

    int wid = tid >> 6, lane = tid & 63;
    int lm = lane & 15, lq = lane >> 4;
    int qw0 = q0 + wid * 16;
    bf8_t aq = *(const bf8_t*)(Qb + (hb * LSEQ + qw0 + lm) * HD + lq * 8);
    float rdv[4];
    #pragma unroll
    for (int r = 0; r < 4; r++)
        rdv[r] = DENSCALE / (float)denI[hb * LSEQ + qw0 + lq * 4 + r];
    __syncthreads();

    const __bf16* Khb = Kb + hb * LSEQ * HD;
    int mbase = kc0 - q0 - 63;
    int qrow = qw0 + lq * 4;
    int* mySloc = Sloc + wid * 320;

    #pragma unroll 4
    for (int sub = 0; sub < 16; sub++) {
        int k0s = kc0 + sub * 16;
        if (k0s + 15 < qw0) continue;               // subtile fully below diagonal
        bf8_t bk_ = *(const bf8_t*)(Khb + (k0s + lm) * HD + lq * 8);
        f4_t z = {0.f, 0.f, 0.f, 0.f};
        f4_t sc = __builtin_amdgcn_mfma_f32_16x16x32_bf16(aq, bk_, z, 0, 0, 0);
        float wvs = wt[sub * 16 + lm];              // w * 2^19
        int kcol = k0s + lm;
        #pragma unroll
        for (int r = 0; r < 4; r++) {
            int m = kcol - (qrow + r);
            if (m >= 0) {
                int iv = __float2int_rn(exp2f(sc[r]) * rdv[r] * wvs);
                atomicAdd(&mySloc[m - mbase], iv);  // native ds_add, wave-private slice
            }
        }
    }
    __syncthreads();
    for (int i = tid; i < 320; i += 256) {
        int m = mbase + i;
        int v = Sloc[i] + Sloc[320 + i] + Sloc[640 + i] + Sloc[960 + i];
        if (m >= 0 && m < LSEQ && v != 0)
            atomicAdd(&S[hb * LSEQ + m], v);        // native int global atomic
    }
}

// ---------------- kernel 3: pooling epilogue (int -> float) ----------------
__global__ __launch_bounds__(256) void k_out(const int* __restrict__ S,
                                             float* __restrict__ out) {
    int idx = blockIdx.x * 256 + threadIdx.x;       // (b*2048 + m)*8 + h
    int h = idx & 7;
    int m = (idx >> 3) & (LSEQ - 1);
    int b = idx >> 14;
    const int* Sr = S + (h * BB + b) * LSEQ;
    float s = (float)Sr[m];
    float cnt = 3.f;
    if (m > 0) s += (float)Sr[m - 1]; else cnt = 2.f;
    if (m < LSEQ - 1) s += (float)Sr[m + 1]; else cnt = 2.f;
    out[idx] = s * RFPSCALE / cnt;
}

extern "C" void kernel_launch(void* const* d_in, const int* in_sizes, int n_in,
                              void* d_out, int out_size, void* d_ws, size_t ws_size,
                              hipStream_t stream) {
    const float* x  = (const float*)d_in[0];
    const float* pe = (const float*)d_in[1];
    const float* Wq = (const float*)d_in[2];
    const float* bq = (const float*)d_in[3];
    const float* Wk = (const float*)d_in[4];
    const float* bk = (const float*)d_in[5];
    const float* Wv = (const float*)d_in[6];
    float* out = (float*)d_out;

    char* ws = (char*)d_ws;
    int*    Si   = (int*)(ws);                              // 128 KB
    float*  w    = (float*)(ws + 131072);                   // 128 KB
    __bf16* Qb   = (__bf16*)(ws + 262144);                  // 2 MB
    __bf16* Kb   = (__bf16*)(ws + 262144 + 2097152);        // 2 MB
    int*    denI = (int*)(ws + 262144 + 4194304);           // 128 KB
    __bf16* WqT  = (__bf16*)(ws + 262144 + 4194304 + 131072);    // 64 KB
    __bf16* WkT  = (__bf16*)(ws + 262144 + 4194304 + 131072 + 65536);

    k_prep<<<448, 256, 0, stream>>>(x, Wq, Wk, Wv, WqT, WkT, w, Si, denI);
    k_qk<<<dim3(256, 8), 256, 0, stream>>>(x, pe, WqT, WkT, bq, bk, Qb, Kb);
    k_den<<<dim3(4, 32, 16), 256, 0, stream>>>(Qb, Kb, denI);
    k_scat<<<dim3(8, 32, 16), 256, 0, stream>>>(Qb, Kb, w, denI, Si);
    k_out<<<128, 256, 0, stream>>>(Si, out);
}